// Round 9
// baseline (158.660 us; speedup 1.0000x reference)
//
#include <hip/hip_runtime.h>
#include <hip/hip_bf16.h>

#define N_NODES 20000
#define N_EDGES 100000
#define IN_DIM  128
#define HID     64
#define LAT     32
#define EDIM    16
#define CH      8      // hh per staged chunk in k_edge
#define NSLICE  32
#define SLICE   (N_EDGES / NSLICE)   // 3125

typedef __attribute__((ext_vector_type(8))) short bf16x8;
typedef __attribute__((ext_vector_type(4))) float f32x4;
typedef __attribute__((ext_vector_type(4))) int   i32x4;

__device__ __forceinline__ short f2bs(float f) {
    __hip_bfloat16 b = __float2bfloat16(f);
    short s;
    __builtin_memcpy(&s, &b, 2);
    return s;
}
__device__ __forceinline__ unsigned pack2(short a, short b) {
    return (unsigned)(unsigned short)a | ((unsigned)(unsigned short)b << 16);
}

// ---------------------------------------------------------------------------
// Fused prep (unchanged from r8): kwA [64][64][24] MFMA-ready rows,
// wT [64][128], rootT [64][64], mlvT [64][64].
// ---------------------------------------------------------------------------
__global__ __launch_bounds__(256) void k_prep(
        const float* __restrict__ kw,     const float* __restrict__ kb,
        const float* __restrict__ lin_w,  const float* __restrict__ root_w,
        const float* __restrict__ mu_w,   const float* __restrict__ lv_w,
        short* __restrict__ kwA,          __hip_bfloat16* __restrict__ wT,
        __hip_bfloat16* __restrict__ rootT, __hip_bfloat16* __restrict__ mlvT) {
    int i = blockIdx.x * 256 + threadIdx.x;
    if (i < 98304) {
        int hh  = i / 1536;
        int rem = i - hh * 1536;
        int oo  = rem / 24;
        int s   = rem - oo * 24;
        int c   = hh * 64 + oo;
        float v = (s < 16) ? kw[s * (HID * HID) + c] : kb[c];
        kwA[i] = f2bs(v);
    } else if (i < 98304 + 8192) {
        int j = i - 98304;
        int o = j >> 7, d = j & 127;
        wT[j] = __float2bfloat16(lin_w[d * HID + o]);
    } else if (i < 98304 + 8192 + 4096) {
        int j = i - (98304 + 8192);
        int o = j >> 6, d = j & 63;
        rootT[j] = __float2bfloat16(root_w[d * HID + o]);
    } else {
        int j = i - (98304 + 8192 + 4096);
        int o2 = j >> 6, k = j & 63;
        mlvT[j] = __float2bfloat16(o2 < 32 ? mu_w[k * LAT + o2]
                                           : lv_w[k * LAT + (o2 - 32)]);
    }
}

// ---------------------------------------------------------------------------
// CSR build 1: per-slice LDS histogram of dst. hist[n][s] (u32).
// ---------------------------------------------------------------------------
__global__ __launch_bounds__(256) void k_hist(const int* __restrict__ ei,
                                              unsigned* __restrict__ hist) {
    __shared__ unsigned hcnt[N_NODES];          // 80 KB
    for (int i = threadIdx.x; i < N_NODES; i += 256) hcnt[i] = 0;
    __syncthreads();
    const int s = blockIdx.x;
    const int base = s * SLICE;
    for (int i = threadIdx.x; i < SLICE; i += 256)
        atomicAdd(&hcnt[ei[N_EDGES + base + i]], 1u);
    __syncthreads();
    for (int i = threadIdx.x; i < N_NODES; i += 256)
        hist[(size_t)i * NSLICE + s] = hcnt[i];
}

// ---------------------------------------------------------------------------
// CSR build 2: per-node exclusive scan over slices (in-place hist -> bases),
// degree out.
// ---------------------------------------------------------------------------
__global__ __launch_bounds__(256) void k_scan_node(unsigned* __restrict__ hist,
                                                   unsigned* __restrict__ deg) {
    int n = blockIdx.x * 256 + threadIdx.x;
    if (n >= N_NODES) return;
    unsigned* row = hist + (size_t)n * NSLICE;
    unsigned acc = 0;
#pragma unroll
    for (int s = 0; s < NSLICE; ++s) {
        unsigned v = row[s]; row[s] = acc; acc += v;
    }
    deg[n] = acc;
}

// ---------------------------------------------------------------------------
// CSR build 3: single-block exclusive scan of deg -> rowptr[0..N].
// ---------------------------------------------------------------------------
__global__ __launch_bounds__(1024) void k_scan(const unsigned* __restrict__ deg,
                                               unsigned* __restrict__ rowptr) {
    __shared__ unsigned v[20480];               // 80 KB
    __shared__ unsigned part[1024];
    const int t = threadIdx.x;
    for (int i = t; i < 20480; i += 1024) v[i] = (i < N_NODES) ? deg[i] : 0;
    __syncthreads();
    unsigned s = 0;
#pragma unroll 4
    for (int i = 0; i < 20; ++i) { s += v[t * 20 + i]; v[t * 20 + i] = s; }
    part[t] = s;
    __syncthreads();
    for (int d = 1; d < 1024; d <<= 1) {
        unsigned x = (t >= d) ? part[t - d] : 0u;
        __syncthreads();
        part[t] += x;
        __syncthreads();
    }
    unsigned base = (t > 0) ? part[t - 1] : 0u;
#pragma unroll 4
    for (int i = 0; i < 20; ++i) {
        int n = t * 20 + i;
        if (n < N_NODES) rowptr[n + 1] = base + v[n];
    }
    if (t == 0) rowptr[0] = 0u;
}

// ---------------------------------------------------------------------------
// CSR build 4: positions. perm[rowptr[dst]+bases[dst][s]+local] = e.
// ---------------------------------------------------------------------------
__global__ __launch_bounds__(256) void k_pos(const int* __restrict__ ei,
                                             const unsigned* __restrict__ bases,
                                             const unsigned* __restrict__ rowptr,
                                             unsigned* __restrict__ perm) {
    __shared__ unsigned off[N_NODES];           // 80 KB
    for (int i = threadIdx.x; i < N_NODES; i += 256) off[i] = 0;
    __syncthreads();
    const int s = blockIdx.x;
    const int base = s * SLICE;
    for (int i = threadIdx.x; i < SLICE; i += 256) {
        int e = base + i;
        int dst = ei[N_EDGES + e];
        unsigned o = atomicAdd(&off[dst], 1u);
        perm[rowptr[dst] + bases[(size_t)dst * NSLICE + s] + o] = (unsigned)e;
    }
}

// ---------------------------------------------------------------------------
// Kernel A (MFMA): h = relu(x @ lin_in_w + lin_in_b)   (unchanged)
// ---------------------------------------------------------------------------
__global__ __launch_bounds__(256) void k_lin_mfma(
        const float* __restrict__ x, const __hip_bfloat16* __restrict__ wT,
        const float* __restrict__ lin_b, float* __restrict__ h) {
    const int n0   = blockIdx.x * 16;
    const int q    = threadIdx.x >> 6;
    const int lane = threadIdx.x & 63;
    const int col  = lane & 15, grp = lane >> 4;
    const int oo   = q * 16 + col;

    f32x4 acc = {0.f, 0.f, 0.f, 0.f};
    const float* xp = x + (size_t)(n0 + col) * IN_DIM + grp * 8;
    const __hip_bfloat16* bp = wT + (size_t)oo * IN_DIM + grp * 8;
#pragma unroll
    for (int it = 0; it < 4; ++it) {
        float4 xa = *(const float4*)(xp + it * 32);
        float4 xb = *(const float4*)(xp + it * 32 + 4);
        bf16x8 af;
        af[0] = f2bs(xa.x); af[1] = f2bs(xa.y); af[2] = f2bs(xa.z); af[3] = f2bs(xa.w);
        af[4] = f2bs(xb.x); af[5] = f2bs(xb.y); af[6] = f2bs(xb.z); af[7] = f2bs(xb.w);
        bf16x8 bfv = *(const bf16x8*)(bp + it * 32);
        acc = __builtin_amdgcn_mfma_f32_16x16x32_bf16(af, bfv, acc, 0, 0, 0);
    }
    const float bias = lin_b[oo];
#pragma unroll
    for (int j = 0; j < 4; ++j) {
        int row = grp * 4 + j;
        h[(size_t)(n0 + row) * HID + oo] = fmaxf(acc[j] + bias, 0.f);
    }
}

// ---------------------------------------------------------------------------
// Kernel B (MFMA, LDS-staged weights, NO ATOMICS): r8 compute core; result
// rows written dense+coalesced to msg[E][64] bf16. Aggregation deferred to
// k_out via CSR (perm/rowptr).
// ---------------------------------------------------------------------------
__global__ __launch_bounds__(512) void k_edge(
        const int* __restrict__ ei, const float* __restrict__ ea,
        const float* __restrict__ h, const short* __restrict__ kwA,
        __hip_bfloat16* __restrict__ msgb) {
    __shared__ __align__(16) short s_a[CH * 64 * 24];   // 24576 B
    __shared__ __align__(16) float s_h[64][68];         // 17408 B

    const int e0   = blockIdx.x * 64;
    const int tid  = threadIdx.x;
    const int w    = tid >> 6;
    const int lane = tid & 63;
    const int q    = w & 3, egp = w >> 2;
    const int col  = lane & 15, grp = lane >> 4;

    for (int i = tid; i < 64 * HID; i += 512) {
        int r = i >> 6, c = i & 63;
        int e = e0 + r; if (e >= N_EDGES) e = N_EDGES - 1;
        int src = ei[e];
        s_h[r][c] = h[(size_t)src * HID + c];
    }

    bf16x8 bfrag[2];
#pragma unroll
    for (int g = 0; g < 2; ++g) {
        bf16x8 b = {};
        if (grp < 2) {
            int e = e0 + (egp * 2 + g) * 16 + col;
            if (e >= N_EDGES) e = N_EDGES - 1;
            const float* ep = ea + (size_t)e * EDIM + grp * 8;
            float4 a0 = *(const float4*)ep;
            float4 a1 = *(const float4*)(ep + 4);
            b[0] = f2bs(a0.x); b[1] = f2bs(a0.y); b[2] = f2bs(a0.z); b[3] = f2bs(a0.w);
            b[4] = f2bs(a1.x); b[5] = f2bs(a1.y); b[6] = f2bs(a1.z); b[7] = f2bs(a1.w);
        } else if (grp == 2) {
            b[0] = (short)0x3F80;     // bf16(1.0) at k=16 -> bias slot
        }
        bfrag[g] = b;
    }

    const int asel  = (grp < 2) ? grp : 2;
    const int abase = (q * 16 + col) * 24 + asel * 8;

    f32x4 msg[2] = {{0.f,0.f,0.f,0.f},{0.f,0.f,0.f,0.f}};
    const f32x4 z4 = {0.f, 0.f, 0.f, 0.f};

    i32x4 st[3];
#pragma unroll
    for (int p = 0; p < 3; ++p)
        st[p] = *(const i32x4*)(kwA + (tid + p * 512) * 8);

#pragma unroll 1
    for (int ch = 0; ch < HID / CH; ++ch) {
        __syncthreads();
#pragma unroll
        for (int p = 0; p < 3; ++p)
            *(i32x4*)(s_a + (tid + p * 512) * 8) = st[p];
        if (ch + 1 < HID / CH) {
            const short* gsrc = kwA + (ch + 1) * (CH * 64 * 24);
#pragma unroll
            for (int p = 0; p < 3; ++p)
                st[p] = *(const i32x4*)(gsrc + (tid + p * 512) * 8);
        }
        __syncthreads();

        int aoff = abase;
#pragma unroll
        for (int hl4 = 0; hl4 < 2; ++hl4) {
            float4 hv0 = *(const float4*)&s_h[(egp * 2 + 0) * 16 + col][ch * CH + hl4 * 4];
            float4 hv1 = *(const float4*)&s_h[(egp * 2 + 1) * 16 + col][ch * CH + hl4 * 4];
#pragma unroll
            for (int u = 0; u < 4; ++u) {
                bf16x8 afr = *(const bf16x8*)(s_a + aoff);
                aoff += 1536;
                f32x4 w0 = __builtin_amdgcn_mfma_f32_16x16x32_bf16(afr, bfrag[0], z4, 0, 0, 0);
                f32x4 w1 = __builtin_amdgcn_mfma_f32_16x16x32_bf16(afr, bfrag[1], z4, 0, 0, 0);
                const float h0 = (u == 0) ? hv0.x : (u == 1) ? hv0.y : (u == 2) ? hv0.z : hv0.w;
                const float h1 = (u == 0) ? hv1.x : (u == 1) ? hv1.y : (u == 2) ? hv1.z : hv1.w;
                msg[0][0] = fmaf(fmaxf(w0[0], 0.f), h0, msg[0][0]);
                msg[0][1] = fmaf(fmaxf(w0[1], 0.f), h0, msg[0][1]);
                msg[0][2] = fmaf(fmaxf(w0[2], 0.f), h0, msg[0][2]);
                msg[0][3] = fmaf(fmaxf(w0[3], 0.f), h0, msg[0][3]);
                msg[1][0] = fmaf(fmaxf(w1[0], 0.f), h1, msg[1][0]);
                msg[1][1] = fmaf(fmaxf(w1[1], 0.f), h1, msg[1][1]);
                msg[1][2] = fmaf(fmaxf(w1[2], 0.f), h1, msg[1][2]);
                msg[1][3] = fmaf(fmaxf(w1[3], 0.f), h1, msg[1][3]);
            }
        }
    }

    // dense write: msg[e][oo], oo = q*16 + grp*4 + {0..3} (8B per group)
#pragma unroll
    for (int g = 0; g < 2; ++g) {
        int e = e0 + (egp * 2 + g) * 16 + col;
        if (e < N_EDGES) {
            uint2 u;
            u.x = pack2(f2bs(msg[g][0]), f2bs(msg[g][1]));
            u.y = pack2(f2bs(msg[g][2]), f2bs(msg[g][3]));
            *(uint2*)(msgb + (size_t)e * HID + q * 16 + grp * 4) = u;
        }
    }
}

// ---------------------------------------------------------------------------
// Kernel C (MFMA): CSR-gather agg + root + heads fused. Block = 16 nodes.
// agg[n,oo] = (sum over p in [rowptr[n],rowptr[n+1]) of msg[perm[p]][oo]) / deg
// ---------------------------------------------------------------------------
__global__ __launch_bounds__(256) void k_out(
        const float* __restrict__ h, const __hip_bfloat16* __restrict__ msgb,
        const unsigned* __restrict__ rowptr, const unsigned* __restrict__ perm,
        const __hip_bfloat16* __restrict__ rootT, const float* __restrict__ conv_b,
        const __hip_bfloat16* __restrict__ mlvT,  const float* __restrict__ mu_b,
        const float* __restrict__ lv_b, float* __restrict__ out) {
    __shared__ __align__(16) __hip_bfloat16 s_h2[16][72];
    const int n0   = blockIdx.x * 16;
    const int q    = threadIdx.x >> 6;
    const int lane = threadIdx.x & 63;
    const int col  = lane & 15, grp = lane >> 4;
    const int oo   = q * 16 + col;

    f32x4 acc = {0.f, 0.f, 0.f, 0.f};
    const float* hp = h + (size_t)(n0 + col) * HID + grp * 8;
    const __hip_bfloat16* bp = rootT + (size_t)oo * HID + grp * 8;
#pragma unroll
    for (int it = 0; it < 2; ++it) {
        float4 xa = *(const float4*)(hp + it * 32);
        float4 xb = *(const float4*)(hp + it * 32 + 4);
        bf16x8 af;
        af[0] = f2bs(xa.x); af[1] = f2bs(xa.y); af[2] = f2bs(xa.z); af[3] = f2bs(xa.w);
        af[4] = f2bs(xb.x); af[5] = f2bs(xb.y); af[6] = f2bs(xb.z); af[7] = f2bs(xb.w);
        bf16x8 bfv = *(const bf16x8*)(bp + it * 32);
        acc = __builtin_amdgcn_mfma_f32_16x16x32_bf16(af, bfv, acc, 0, 0, 0);
    }
    const float cb = conv_b[oo];
#pragma unroll
    for (int j = 0; j < 4; ++j) {
        int row = grp * 4 + j;
        int n = n0 + row;
        unsigned p0 = rowptr[n], p1 = rowptr[n + 1];
        float agg = 0.f;
        for (unsigned p = p0; p < p1; ++p) {
            unsigned e = perm[p];
            agg += __bfloat162float(msgb[(size_t)e * HID + oo]);
        }
        agg /= fmaxf((float)(p1 - p0), 1.f);
        s_h2[row][oo] = __float2bfloat16(fmaxf(acc[j] + agg + cb, 0.f));
    }
    __syncthreads();

    f32x4 acc2 = {0.f, 0.f, 0.f, 0.f};
    const __hip_bfloat16* b2 = mlvT + (size_t)oo * HID + grp * 8;
#pragma unroll
    for (int it = 0; it < 2; ++it) {
        bf16x8 af = *(const bf16x8*)((const char*)&s_h2[col][0] + it * 64 + grp * 16);
        bf16x8 bfv = *(const bf16x8*)(b2 + it * 32);
        acc2 = __builtin_amdgcn_mfma_f32_16x16x32_bf16(af, bfv, acc2, 0, 0, 0);
    }
    const float bias = (oo < 32) ? mu_b[oo] : lv_b[oo - 32];
    float* obase = (oo < 32) ? (out + oo) : (out + (size_t)N_NODES * LAT + (oo - 32));
#pragma unroll
    for (int j = 0; j < 4; ++j) {
        int n = n0 + grp * 4 + j;
        obase[(size_t)n * LAT] = acc2[j] + bias;
    }
}

// ---------------------------------------------------------------------------
extern "C" void kernel_launch(void* const* d_in, const int* in_sizes, int n_in,
                              void* d_out, int out_size, void* d_ws, size_t ws_size,
                              hipStream_t stream) {
    const float* x      = (const float*)d_in[0];
    const int*   ei     = (const int*)  d_in[1];
    const float* ea     = (const float*)d_in[2];
    const float* lin_w  = (const float*)d_in[3];
    const float* lin_b  = (const float*)d_in[4];
    const float* kw     = (const float*)d_in[5];
    const float* kb     = (const float*)d_in[6];
    const float* root_w = (const float*)d_in[7];
    const float* conv_b = (const float*)d_in[8];
    const float* mu_w   = (const float*)d_in[9];
    const float* mu_b   = (const float*)d_in[10];
    const float* lv_w   = (const float*)d_in[11];
    const float* lv_b   = (const float*)d_in[12];
    float* out = (float*)d_out;

    char* p = (char*)d_ws;
    float*          h      = (float*)p;           p += (size_t)N_NODES * HID * 4;   // 5.12 MB
    __hip_bfloat16* msgb   = (__hip_bfloat16*)p;  p += (size_t)N_EDGES * HID * 2;   // 12.8 MB
    unsigned*       hist   = (unsigned*)p;        p += (size_t)N_NODES * NSLICE * 4;// 2.56 MB
    unsigned*       deg    = (unsigned*)p;        p += (size_t)N_NODES * 4;
    unsigned*       rowptr = (unsigned*)p;        p += (size_t)(N_NODES + 1) * 4;
    unsigned*       perm   = (unsigned*)p;        p += (size_t)N_EDGES * 4;
    short*          kwA    = (short*)p;           p += 98304 * 2;
    __hip_bfloat16* wT     = (__hip_bfloat16*)p;  p += 8192 * 2;
    __hip_bfloat16* rootT  = (__hip_bfloat16*)p;  p += 4096 * 2;
    __hip_bfloat16* mlvT   = (__hip_bfloat16*)p;  p += 4096 * 2;

    k_prep<<<448, 256, 0, stream>>>(kw, kb, lin_w, root_w, mu_w, lv_w,
                                    kwA, wT, rootT, mlvT);

    k_hist<<<NSLICE, 256, 0, stream>>>(ei, hist);
    k_scan_node<<<(N_NODES + 255) / 256, 256, 0, stream>>>(hist, deg);
    k_scan<<<1, 1024, 0, stream>>>(deg, rowptr);
    k_pos<<<NSLICE, 256, 0, stream>>>(ei, hist, rowptr, perm);

    k_lin_mfma<<<N_NODES / 16, 256, 0, stream>>>(x, wT, lin_b, h);

    k_edge<<<(N_EDGES + 63) / 64, 512, 0, stream>>>(ei, ea, h, kwA, msgb);

    k_out<<<N_NODES / 16, 256, 0, stream>>>(h, msgb, rowptr, perm, rootT, conv_b,
                                            mlvT, mu_b, lv_b, out);
}